// Round 5
// baseline (183.945 us; speedup 1.0000x reference)
//
#include <hip/hip_runtime.h>
#include <hip/hip_fp16.h>

typedef _Float16 f16x8 __attribute__((ext_vector_type(8)));
typedef _Float16 f16x4 __attribute__((ext_vector_type(4)));
typedef float f32x4 __attribute__((ext_vector_type(4)));

#define NB 8
#define NNS 5

// workspace float offsets
// xpT  : 2M halfs = 1M float slots  [0, 1048576)
// srcT : 32768  [1048576, 1081344)   layout [b][h][j] f32
// dstT : 32768  [1081344, 1114112)   layout [b][h][i] f32
// xmean: 2048   [1114112, 1116160)
// cs   : 8      [1116160, 1116168)
// WpTh : 64K halfs = 32768 floats [1116168, 1148936)

// ---------------------------------------------------------------------------
// K0 merged: blocks [0,256): WpTh[f][k] = fp16(Wp[k][f]);
//            blocks [256,512): xmean atomic partials over 32 rows.
// ---------------------------------------------------------------------------
__global__ __launch_bounds__(256) void k_pre(const float* __restrict__ Wp,
                                             const float* __restrict__ x,
                                             __half* __restrict__ WpTh,
                                             float* __restrict__ xmean) {
  const int t = threadIdx.x;
  int blk = blockIdx.x;
  if (blk < 256) {
    WpTh[(t << 8) + blk] = __float2half(Wp[(blk << 8) + t]);
  } else {
    blk -= 256;
    const int row0 = blk << 5;
    const int b = row0 >> 10;
    float ps = 0.f;
    #pragma unroll 8
    for (int r = 0; r < 32; ++r) ps += x[(size_t)(row0 + r) * 256 + t];
    atomicAdd(&xmean[(b << 8) + t], ps);
  }
}

// ---------------------------------------------------------------------------
// K1: xpT[b*256+f][i] = fp16(x @ Wp + bp) via MFMA 16x16x32 f16, PLUS fused
// src/dst head-scores from the accumulators (head h == col-quarter nh).
// Grid 512: bm = blk>>2 (64-row group), nh = blk&3. Wave w: rows bm*64+w*16.
// ---------------------------------------------------------------------------
__global__ __launch_bounds__(256, 4) void k_projM(
    const float* __restrict__ x, const __half* __restrict__ WpTh,
    const float* __restrict__ bp, const float* __restrict__ att_w,
    __half* __restrict__ xpT, float* __restrict__ srcT,
    float* __restrict__ dstT) {
  const int t = threadIdx.x;
  const int l = t & 63, w = t >> 6;
  const int lm = l & 15, q = l >> 4;
  const int bm = blockIdx.x >> 2, nh = blockIdx.x & 3;
  const int R0 = (bm << 6) + (w << 4);
  const int f0 = nh << 6;

  // A-fragments: row R0+lm, k = kk*32 + q*8 + [0..7], f32 -> f16 in-reg
  const float* arow = x + (size_t)(R0 + lm) * 256 + (q << 3);
  f16x8 ah[8];
  #pragma unroll
  for (int kk = 0; kk < 8; ++kk) {
    const f32x4 xa = *(const f32x4*)(arow + (kk << 5));
    const f32x4 xb = *(const f32x4*)(arow + (kk << 5) + 4);
    f16x8 v;
    #pragma unroll
    for (int u = 0; u < 4; ++u) {
      v[u] = (_Float16)xa[u];
      v[u + 4] = (_Float16)xb[u];
    }
    ah[kk] = v;
  }

  f32x4 acc[4];
  #pragma unroll
  for (int n = 0; n < 4; ++n) acc[n] = (f32x4){0.f, 0.f, 0.f, 0.f};
  #pragma unroll
  for (int n = 0; n < 4; ++n) {
    const __half* brow = WpTh + (size_t)(f0 + (n << 4) + lm) * 256 + (q << 3);
    #pragma unroll
    for (int kk = 0; kk < 8; ++kk) {
      const f16x8 bf = *(const f16x8*)(brow + (kk << 5));
      acc[n] = __builtin_amdgcn_mfma_f32_16x16x32_f16(ah[kk], bf, acc[n],
                                                      0, 0, 0);
    }
  }

  // epilogue: C/D layout col = lane&15, row = (lane>>4)*4 + reg
  const int b = R0 >> 10;
  const int il = (R0 & 1023) + (q << 2);
  float wsn[4], wdn[4];
  #pragma unroll
  for (int n = 0; n < 4; ++n) {
    const int d = (n << 4) + lm;      // d within head (f0 = nh*64)
    wsn[n] = att_w[d];
    wdn[n] = att_w[64 + d];
  }
  #pragma unroll
  for (int n = 0; n < 4; ++n) {
    const int f = f0 + (n << 4) + lm;
    const float bias = bp[f];
    f16x4 o;
    #pragma unroll
    for (int reg = 0; reg < 4; ++reg) {
      acc[n][reg] += bias;
      o[reg] = (_Float16)acc[n][reg];
    }
    *(f16x4*)(xpT + (((size_t)((b << 8) + f)) << 10) + il) = o;
  }
  #pragma unroll
  for (int reg = 0; reg < 4; ++reg) {
    float ss = 0.f, ds = 0.f;
    #pragma unroll
    for (int n = 0; n < 4; ++n) {
      ss = fmaf(acc[n][reg], wsn[n], ss);
      ds = fmaf(acc[n][reg], wdn[n], ds);
    }
    #pragma unroll
    for (int off = 1; off < 16; off <<= 1) {
      ss += __shfl_xor(ss, off);
      ds += __shfl_xor(ds, off);
    }
    if (lm == 0) {
      const int i = il + reg;
      srcT[(((b << 2) + nh) << 10) + i] = ss;
      dstT[(((b << 2) + nh) << 10) + i] = ds;
    }
  }
}

// ---------------------------------------------------------------------------
// K2: tiny per-batch MLP head -> s_logits (output 1), c_s scalar.
// First GEMV split 2-way over k for latency.
// ---------------------------------------------------------------------------
__global__ __launch_bounds__(256) void k_head(
    const float* __restrict__ Ws1, const float* __restrict__ bs1,
    const float* __restrict__ Ws2, const float* __restrict__ bs2,
    const float* __restrict__ Wc1, const float* __restrict__ bc1,
    const float* __restrict__ Wc2, const float* __restrict__ bc2,
    const float* __restrict__ att_w, const float* __restrict__ xmean,
    float* __restrict__ cs_ws, float* __restrict__ out_slogits) {
  __shared__ float xm[256];
  __shared__ float h1p[2][128];
  __shared__ float h1[128];
  __shared__ float sl[NNS];
  __shared__ float sp[NNS];
  __shared__ float cc1[64];
  __shared__ float cvec[64];
  const int b = blockIdx.x, t = threadIdx.x;
  xm[t] = xmean[b * 256 + t] * (1.f / 1024.f);
  __syncthreads();
  {
    const int kh = t >> 7, f = t & 127;
    const float* wcol = Ws1 + (kh << 7) * 128 + f;
    const float* xk = xm + (kh << 7);
    float a = 0.f;
    #pragma unroll 8
    for (int k = 0; k < 128; ++k) a = fmaf(xk[k], wcol[k * 128], a);
    h1p[kh][f] = a;
  }
  __syncthreads();
  if (t < 128) h1[t] = fmaxf(h1p[0][t] + h1p[1][t] + bs1[t], 0.f);
  __syncthreads();
  if (t < NNS) {
    float a = bs2[t];
    #pragma unroll 8
    for (int k = 0; k < 128; ++k) a = fmaf(h1[k], Ws2[k * NNS + t], a);
    sl[t] = a;
    out_slogits[b * NNS + t] = a;
  }
  __syncthreads();
  if (t == 0) {
    float m = sl[0];
    for (int n = 1; n < NNS; ++n) m = fmaxf(m, sl[n]);
    float s = 0.f;
    for (int n = 0; n < NNS; ++n) { sp[n] = expf(sl[n] - m); s += sp[n]; }
    for (int n = 0; n < NNS; ++n) sp[n] /= s;
  }
  __syncthreads();
  if (t < 64) {
    float a = bc1[t];
    #pragma unroll
    for (int n = 0; n < NNS; ++n) a = fmaf(sp[n], Wc1[n * 64 + t], a);
    cc1[t] = fmaxf(a, 0.f);
  }
  __syncthreads();
  if (t < 64) {
    float a = bc2[t];
    #pragma unroll 8
    for (int m = 0; m < 64; ++m) a = fmaf(cc1[m], Wc2[m * 64 + t], a);
    cvec[t] = a;
  }
  __syncthreads();
  if (t < 64) {
    float v = cvec[t] * att_w[128 + t];
    #pragma unroll
    for (int m = 32; m; m >>= 1) v += __shfl_xor(v, m);
    if (t == 0) cs_ws[b] = v;
  }
}

// ---------------------------------------------------------------------------
// K3: attention — barrier-free, LDS-free. Wave = (b, 16-row tile, h, dhalf).
// Lane l computes exp-weights for row i0+(l&15), j = kk*32+(l>>4)*8+[0..8)
// directly in the MFMA A-fragment layout, packs f16, MFMA against xpT.
// Denominator: per-lane partial sum, shfl_xor(16,32), normalize epilogue.
// ---------------------------------------------------------------------------
__global__ __launch_bounds__(256, 4) void k_attn(
    const __half* __restrict__ xpT, const float* __restrict__ A,
    const float* __restrict__ srcT, const float* __restrict__ dstT,
    const float* __restrict__ cs_ws, const float* __restrict__ lam,
    float* __restrict__ out) {
  const int t = threadIdx.x;
  const int l = t & 63, h = t >> 6;          // wave id == head
  const int lm = l & 15, q = l >> 4;
  const int blk = blockIdx.x;
  const int b = blk >> 7;
  const int tile = (blk >> 1) & 63;
  const int dh = blk & 1;
  const int i0 = tile << 4;

  const float csv = cs_ws[b];
  const float lamln2 = lam[h] * 0.69314718056f;   // lam*ln(A) = lamln2*log2(A)
  const float dstc = dstT[(((b << 2) + h) << 10) + i0 + lm] + csv;
  const float* Arow = A + (size_t)(i0 + lm) * 1024;
  const float* srcb = srcT + (((b << 2) + h) << 10);
  const __half* xb0 =
      xpT + (((size_t)((b << 8) + (h << 6) + (dh << 5) + lm)) << 10);
  const __half* xb1 = xb0 + (16 << 10);

  f32x4 acc0 = {0.f, 0.f, 0.f, 0.f};
  f32x4 acc1 = {0.f, 0.f, 0.f, 0.f};
  float sum = 0.f;

  #pragma unroll 2
  for (int kk = 0; kk < 32; ++kk) {
    const int j0 = (kk << 5) + (q << 3);
    const f32x4 a0 = *(const f32x4*)(Arow + j0);
    const f32x4 a1 = *(const f32x4*)(Arow + j0 + 4);
    const f32x4 s0 = *(const f32x4*)(srcb + j0);
    const f32x4 s1 = *(const f32x4*)(srcb + j0 + 4);
    const f16x8 bf0 = *(const f16x8*)(xb0 + j0);
    const f16x8 bf1 = *(const f16x8*)(xb1 + j0);
    f16x8 af;
    #pragma unroll
    for (int u = 0; u < 4; ++u) {
      {
        const float la = __log2f(a0[u] + 1e-9f);
        const float e = s0[u] + dstc;
        const float lk = fmaxf(e, 0.2f * e);        // leaky relu 0.2
        const float p = __expf(fmaf(lamln2, la, lk));
        sum += p;
        af[u] = (_Float16)p;
      }
      {
        const float la = __log2f(a1[u] + 1e-9f);
        const float e = s1[u] + dstc;
        const float lk = fmaxf(e, 0.2f * e);
        const float p = __expf(fmaf(lamln2, la, lk));
        sum += p;
        af[u + 4] = (_Float16)p;
      }
    }
    acc0 = __builtin_amdgcn_mfma_f32_16x16x32_f16(af, bf0, acc0, 0, 0, 0);
    acc1 = __builtin_amdgcn_mfma_f32_16x16x32_f16(af, bf1, acc1, 0, 0, 0);
  }

  // row denominators: combine the 4 j-subsets (lanes with equal l&15)
  sum += __shfl_xor(sum, 16);
  sum += __shfl_xor(sum, 32);
  const float dinv_l = 1.f / sum;                  // valid for row i0+lm

  // C/D layout: col = lane&15, row = (lane>>4)*4 + reg
  float* ob =
      out + (((size_t)((b << 10) + i0)) << 8) + (h << 6) + (dh << 5) + lm;
  #pragma unroll
  for (int reg = 0; reg < 4; ++reg) {
    const int mrow = (q << 2) + reg;
    const float dv = __shfl(dinv_l, mrow);         // lane mrow holds row mrow
    ob[(size_t)mrow << 8] = acc0[reg] * dv;
    ob[((size_t)mrow << 8) + 16] = acc1[reg] * dv;
  }
}

extern "C" void kernel_launch(void* const* d_in, const int* in_sizes, int n_in,
                              void* d_out, int out_size, void* d_ws,
                              size_t ws_size, hipStream_t stream) {
  const float* x     = (const float*)d_in[0];
  const float* A     = (const float*)d_in[1];
  const float* Wp    = (const float*)d_in[2];
  const float* bp    = (const float*)d_in[3];
  const float* Ws1   = (const float*)d_in[4];
  const float* bs1   = (const float*)d_in[5];
  const float* Ws2   = (const float*)d_in[6];
  const float* bs2   = (const float*)d_in[7];
  const float* Wc1   = (const float*)d_in[8];
  const float* bc1   = (const float*)d_in[9];
  const float* Wc2   = (const float*)d_in[10];
  const float* bc2   = (const float*)d_in[11];
  const float* att_w = (const float*)d_in[12];
  const float* lam   = (const float*)d_in[13];
  float* out = (float*)d_out;
  float* ws  = (float*)d_ws;

  __half* xpT  = (__half*)ws;             // 2M halfs
  float* srcT  = ws + 1048576;
  float* dstT  = ws + 1081344;
  float* xmean = ws + 1114112;
  float* cs    = ws + 1116160;
  __half* WpTh = (__half*)(ws + 1116168);

  hipMemsetAsync(xmean, 0, 2048 * sizeof(float), stream);

  k_pre<<<dim3(512), dim3(256), 0, stream>>>(Wp, x, WpTh, xmean);
  k_projM<<<dim3(512), dim3(256), 0, stream>>>(x, WpTh, bp, att_w, xpT, srcT,
                                               dstT);
  k_head<<<dim3(NB), dim3(256), 0, stream>>>(Ws1, bs1, Ws2, bs2, Wc1, bc1,
                                             Wc2, bc2, att_w, xmean, cs,
                                             out + NB * 1024 * 256);
  k_attn<<<dim3(1024), dim3(256), 0, stream>>>(xpT, A, srcT, dstT, cs, lam,
                                               out);
}

// Round 6
// 159.434 us; speedup vs baseline: 1.1537x; 1.1537x over previous
//
#include <hip/hip_runtime.h>
#include <hip/hip_fp16.h>

typedef _Float16 f16x8 __attribute__((ext_vector_type(8)));
typedef _Float16 f16x4 __attribute__((ext_vector_type(4)));
typedef float f32x4 __attribute__((ext_vector_type(4)));

#define NB 8
#define NNS 5

// workspace float offsets
// xpT  : 2M halfs = 1M float slots  [0, 1048576)
// l2A  : 1M halfs = 512K floats     [1048576, 1572864)   fp16 log2(A+1e-9)
// srcT : 32768  [1572864, 1605632)   layout [b][h][j] f32
// dstT : 32768  [1605632, 1638400)   layout [b][h][i] f32
// xmean: 2048   [1638400, 1640448)
// cs   : 8      [1640448, 1640456)
// WpTh : 64K halfs = 32768 floats   [1640456, 1673224)

// ---------------------------------------------------------------------------
// K0 merged: blocks [0,256): WpTh[f][k] = fp16(Wp[k][f]);
//            blocks [256,512): xmean atomic partials over 32 rows;
//            blocks [512,4608): l2A = fp16(log2(A + 1e-9)).
// ---------------------------------------------------------------------------
__global__ __launch_bounds__(256) void k_pre(const float* __restrict__ Wp,
                                             const float* __restrict__ x,
                                             const float* __restrict__ A,
                                             __half* __restrict__ WpTh,
                                             float* __restrict__ xmean,
                                             __half* __restrict__ l2A) {
  const int t = threadIdx.x;
  int blk = blockIdx.x;
  if (blk < 256) {
    WpTh[(t << 8) + blk] = __float2half(Wp[(blk << 8) + t]);
  } else if (blk < 512) {
    blk -= 256;
    const int row0 = blk << 5;
    const int b = row0 >> 10;
    float ps = 0.f;
    #pragma unroll 8
    for (int r = 0; r < 32; ++r) ps += x[(size_t)(row0 + r) * 256 + t];
    atomicAdd(&xmean[(b << 8) + t], ps);
  } else {
    const int idx = ((blk - 512) << 8) + t;
    l2A[idx] = __float2half(__log2f(A[idx] + 1e-9f));
  }
}

// ---------------------------------------------------------------------------
// K1: xpT[b*256+f][i] = fp16(x @ Wp + bp) via MFMA 16x16x32 f16, PLUS fused
// src/dst head-scores from the accumulators (head h == col-quarter nh).
// Grid 512: bm = blk>>2 (64-row group), nh = blk&3. Wave w: rows bm*64+w*16.
// ---------------------------------------------------------------------------
__global__ __launch_bounds__(256, 4) void k_projM(
    const float* __restrict__ x, const __half* __restrict__ WpTh,
    const float* __restrict__ bp, const float* __restrict__ att_w,
    __half* __restrict__ xpT, float* __restrict__ srcT,
    float* __restrict__ dstT) {
  const int t = threadIdx.x;
  const int l = t & 63, w = t >> 6;
  const int lm = l & 15, q = l >> 4;
  const int bm = blockIdx.x >> 2, nh = blockIdx.x & 3;
  const int R0 = (bm << 6) + (w << 4);
  const int f0 = nh << 6;

  const float* arow = x + (size_t)(R0 + lm) * 256 + (q << 3);
  f16x8 ah[8];
  #pragma unroll
  for (int kk = 0; kk < 8; ++kk) {
    const f32x4 xa = *(const f32x4*)(arow + (kk << 5));
    const f32x4 xb = *(const f32x4*)(arow + (kk << 5) + 4);
    f16x8 v;
    #pragma unroll
    for (int u = 0; u < 4; ++u) {
      v[u] = (_Float16)xa[u];
      v[u + 4] = (_Float16)xb[u];
    }
    ah[kk] = v;
  }

  f32x4 acc[4];
  #pragma unroll
  for (int n = 0; n < 4; ++n) acc[n] = (f32x4){0.f, 0.f, 0.f, 0.f};
  #pragma unroll
  for (int n = 0; n < 4; ++n) {
    const __half* brow = WpTh + (size_t)(f0 + (n << 4) + lm) * 256 + (q << 3);
    #pragma unroll
    for (int kk = 0; kk < 8; ++kk) {
      const f16x8 bf = *(const f16x8*)(brow + (kk << 5));
      acc[n] = __builtin_amdgcn_mfma_f32_16x16x32_f16(ah[kk], bf, acc[n],
                                                      0, 0, 0);
    }
  }

  const int b = R0 >> 10;
  const int il = (R0 & 1023) + (q << 2);
  float wsn[4], wdn[4];
  #pragma unroll
  for (int n = 0; n < 4; ++n) {
    const int d = (n << 4) + lm;
    wsn[n] = att_w[d];
    wdn[n] = att_w[64 + d];
  }
  #pragma unroll
  for (int n = 0; n < 4; ++n) {
    const int f = f0 + (n << 4) + lm;
    const float bias = bp[f];
    f16x4 o;
    #pragma unroll
    for (int reg = 0; reg < 4; ++reg) {
      acc[n][reg] += bias;
      o[reg] = (_Float16)acc[n][reg];
    }
    *(f16x4*)(xpT + (((size_t)((b << 8) + f)) << 10) + il) = o;
  }
  #pragma unroll
  for (int reg = 0; reg < 4; ++reg) {
    float ss = 0.f, ds = 0.f;
    #pragma unroll
    for (int n = 0; n < 4; ++n) {
      ss = fmaf(acc[n][reg], wsn[n], ss);
      ds = fmaf(acc[n][reg], wdn[n], ds);
    }
    #pragma unroll
    for (int off = 1; off < 16; off <<= 1) {
      ss += __shfl_xor(ss, off);
      ds += __shfl_xor(ds, off);
    }
    if (lm == 0) {
      const int i = il + reg;
      srcT[(((b << 2) + nh) << 10) + i] = ss;
      dstT[(((b << 2) + nh) << 10) + i] = ds;
    }
  }
}

// ---------------------------------------------------------------------------
// K2: tiny per-batch MLP head -> s_logits (output 1), c_s scalar.
// ---------------------------------------------------------------------------
__global__ __launch_bounds__(256) void k_head(
    const float* __restrict__ Ws1, const float* __restrict__ bs1,
    const float* __restrict__ Ws2, const float* __restrict__ bs2,
    const float* __restrict__ Wc1, const float* __restrict__ bc1,
    const float* __restrict__ Wc2, const float* __restrict__ bc2,
    const float* __restrict__ att_w, const float* __restrict__ xmean,
    float* __restrict__ cs_ws, float* __restrict__ out_slogits) {
  __shared__ float xm[256];
  __shared__ float h1p[2][128];
  __shared__ float h1[128];
  __shared__ float sl[NNS];
  __shared__ float sp[NNS];
  __shared__ float cc1[64];
  __shared__ float cvec[64];
  const int b = blockIdx.x, t = threadIdx.x;
  xm[t] = xmean[b * 256 + t] * (1.f / 1024.f);
  __syncthreads();
  {
    const int kh = t >> 7, f = t & 127;
    const float* wcol = Ws1 + (kh << 7) * 128 + f;
    const float* xk = xm + (kh << 7);
    float a = 0.f;
    #pragma unroll 8
    for (int k = 0; k < 128; ++k) a = fmaf(xk[k], wcol[k * 128], a);
    h1p[kh][f] = a;
  }
  __syncthreads();
  if (t < 128) h1[t] = fmaxf(h1p[0][t] + h1p[1][t] + bs1[t], 0.f);
  __syncthreads();
  if (t < NNS) {
    float a = bs2[t];
    #pragma unroll 8
    for (int k = 0; k < 128; ++k) a = fmaf(h1[k], Ws2[k * NNS + t], a);
    sl[t] = a;
    out_slogits[b * NNS + t] = a;
  }
  __syncthreads();
  if (t == 0) {
    float m = sl[0];
    for (int n = 1; n < NNS; ++n) m = fmaxf(m, sl[n]);
    float s = 0.f;
    for (int n = 0; n < NNS; ++n) { sp[n] = expf(sl[n] - m); s += sp[n]; }
    for (int n = 0; n < NNS; ++n) sp[n] /= s;
  }
  __syncthreads();
  if (t < 64) {
    float a = bc1[t];
    #pragma unroll
    for (int n = 0; n < NNS; ++n) a = fmaf(sp[n], Wc1[n * 64 + t], a);
    cc1[t] = fmaxf(a, 0.f);
  }
  __syncthreads();
  if (t < 64) {
    float a = bc2[t];
    #pragma unroll 8
    for (int m = 0; m < 64; ++m) a = fmaf(cc1[m], Wc2[m * 64 + t], a);
    cvec[t] = a;
  }
  __syncthreads();
  if (t < 64) {
    float v = cvec[t] * att_w[128 + t];
    #pragma unroll
    for (int m = 32; m; m >>= 1) v += __shfl_xor(v, m);
    if (t == 0) cs_ws[b] = v;
  }
}

// ---------------------------------------------------------------------------
// K3: attention. Block = (b, 16-row tile), 512 threads = 8 waves.
// Wave w = (h=w&3, jh=w>>2): scores for its 512-j half computed ONCE in the
// MFMA A-fragment layout (registers, no LDS), full d=64 via 4 MFMAs/k-step.
// Manual 1-deep prefetch of all loads. One barrier: cross-jh accumulator +
// denominator reduce through padded LDS.
// ---------------------------------------------------------------------------
__global__ __launch_bounds__(512, 4) void k_attn(
    const __half* __restrict__ xpT, const __half* __restrict__ l2A,
    const float* __restrict__ srcT, const float* __restrict__ dstT,
    const float* __restrict__ cs_ws, const float* __restrict__ lam,
    float* __restrict__ out) {
  __shared__ float red[4][4][16][17];   // [h][n][irow][dcol] (+pad)
  __shared__ float dsum[4][2][16];
  const int t = threadIdx.x;
  const int l = t & 63, w = t >> 6;
  const int h = w & 3, jh = w >> 2;
  const int lm = l & 15, q = l >> 4;
  const int b = blockIdx.x >> 6;
  const int i0 = (blockIdx.x & 63) << 4;

  const float csv = cs_ws[b];
  const float lamln2 = lam[h] * 0.69314718056f;  // lam*ln(A) = lamln2*log2(A)
  const float dstc = dstT[(((b << 2) + h) << 10) + i0 + lm] + csv;
  const int jb = (jh << 9) + (q << 3);

  const __half* Lp = l2A + (size_t)(i0 + lm) * 1024 + jb;
  const float* Sp = srcT + (((b << 2) + h) << 10) + jb;
  const __half* B0 = xpT + (((size_t)((b << 8) + (h << 6) + lm)) << 10) + jb;
  const __half* B1 = B0 + (16 << 10);
  const __half* B2 = B0 + (32 << 10);
  const __half* B3 = B0 + (48 << 10);

  f32x4 acc[4];
  #pragma unroll
  for (int n = 0; n < 4; ++n) acc[n] = (f32x4){0.f, 0.f, 0.f, 0.f};
  float sum = 0.f;

  f16x8 la = *(const f16x8*)Lp;
  f32x4 s0 = *(const f32x4*)Sp;
  f32x4 s1 = *(const f32x4*)(Sp + 4);
  f16x8 bf0 = *(const f16x8*)B0;
  f16x8 bf1 = *(const f16x8*)B1;
  f16x8 bf2 = *(const f16x8*)B2;
  f16x8 bf3 = *(const f16x8*)B3;

  #pragma unroll 4
  for (int kk = 0; kk < 16; ++kk) {
    const int off = (kk < 15) ? ((kk + 1) << 5) : (kk << 5);
    const f16x8 la_n = *(const f16x8*)(Lp + off);
    const f32x4 s0_n = *(const f32x4*)(Sp + off);
    const f32x4 s1_n = *(const f32x4*)(Sp + off + 4);
    const f16x8 b0_n = *(const f16x8*)(B0 + off);
    const f16x8 b1_n = *(const f16x8*)(B1 + off);
    const f16x8 b2_n = *(const f16x8*)(B2 + off);
    const f16x8 b3_n = *(const f16x8*)(B3 + off);

    f16x8 af;
    #pragma unroll
    for (int u = 0; u < 4; ++u) {
      {
        const float e = s0[u] + dstc;
        const float lk = fmaxf(e, 0.2f * e);          // leaky relu 0.2
        const float p = __expf(fmaf(lamln2, (float)la[u], lk));
        sum += p;
        af[u] = (_Float16)p;
      }
      {
        const float e = s1[u] + dstc;
        const float lk = fmaxf(e, 0.2f * e);
        const float p = __expf(fmaf(lamln2, (float)la[u + 4], lk));
        sum += p;
        af[u + 4] = (_Float16)p;
      }
    }
    acc[0] = __builtin_amdgcn_mfma_f32_16x16x32_f16(af, bf0, acc[0], 0, 0, 0);
    acc[1] = __builtin_amdgcn_mfma_f32_16x16x32_f16(af, bf1, acc[1], 0, 0, 0);
    acc[2] = __builtin_amdgcn_mfma_f32_16x16x32_f16(af, bf2, acc[2], 0, 0, 0);
    acc[3] = __builtin_amdgcn_mfma_f32_16x16x32_f16(af, bf3, acc[3], 0, 0, 0);
    la = la_n; s0 = s0_n; s1 = s1_n;
    bf0 = b0_n; bf1 = b1_n; bf2 = b2_n; bf3 = b3_n;
  }

  // row-sums over this jh half: lanes sharing lm combine
  sum += __shfl_xor(sum, 16);
  sum += __shfl_xor(sum, 32);
  if (l < 16) dsum[h][jh][lm] = sum;      // lane lm holds row lm
  if (jh == 0) {
    #pragma unroll
    for (int n = 0; n < 4; ++n)
      #pragma unroll
      for (int reg = 0; reg < 4; ++reg)
        red[h][n][(q << 2) + reg][lm] = acc[n][reg];
  }
  __syncthreads();
  if (jh == 1) {
    // C/D layout: dcol = lane&15, irow = (lane>>4)*4 + reg
    float* ob = out + (((size_t)((b << 10) + i0)) << 8) + (h << 6) + lm;
    #pragma unroll
    for (int reg = 0; reg < 4; ++reg) {
      const int mrow = (q << 2) + reg;
      const float dv = 1.f / (dsum[h][0][mrow] + dsum[h][1][mrow]);
      #pragma unroll
      for (int n = 0; n < 4; ++n) {
        const float val = (acc[n][reg] + red[h][n][mrow][lm]) * dv;
        ob[(((size_t)mrow) << 8) + (n << 4)] = val;
      }
    }
  }
}

extern "C" void kernel_launch(void* const* d_in, const int* in_sizes, int n_in,
                              void* d_out, int out_size, void* d_ws,
                              size_t ws_size, hipStream_t stream) {
  const float* x     = (const float*)d_in[0];
  const float* A     = (const float*)d_in[1];
  const float* Wp    = (const float*)d_in[2];
  const float* bp    = (const float*)d_in[3];
  const float* Ws1   = (const float*)d_in[4];
  const float* bs1   = (const float*)d_in[5];
  const float* Ws2   = (const float*)d_in[6];
  const float* bs2   = (const float*)d_in[7];
  const float* Wc1   = (const float*)d_in[8];
  const float* bc1   = (const float*)d_in[9];
  const float* Wc2   = (const float*)d_in[10];
  const float* bc2   = (const float*)d_in[11];
  const float* att_w = (const float*)d_in[12];
  const float* lam   = (const float*)d_in[13];
  float* out = (float*)d_out;
  float* ws  = (float*)d_ws;

  __half* xpT  = (__half*)ws;                 // 2M halfs
  __half* l2A  = (__half*)(ws + 1048576);     // 1M halfs
  float* srcT  = ws + 1572864;
  float* dstT  = ws + 1605632;
  float* xmean = ws + 1638400;
  float* cs    = ws + 1640448;
  __half* WpTh = (__half*)(ws + 1640456);

  hipMemsetAsync(xmean, 0, 2048 * sizeof(float), stream);

  k_pre<<<dim3(4608), dim3(256), 0, stream>>>(Wp, x, A, WpTh, xmean, l2A);
  k_projM<<<dim3(512), dim3(256), 0, stream>>>(x, WpTh, bp, att_w, xpT, srcT,
                                               dstT);
  k_head<<<dim3(NB), dim3(256), 0, stream>>>(Ws1, bs1, Ws2, bs2, Wc1, bc1,
                                             Wc2, bc2, att_w, xmean, cs,
                                             out + NB * 1024 * 256);
  k_attn<<<dim3(512), dim3(512), 0, stream>>>(xpT, l2A, srcT, dstT, cs, lam,
                                              out);
}

// Round 7
// 129.962 us; speedup vs baseline: 1.4154x; 1.2268x over previous
//
#include <hip/hip_runtime.h>
#include <hip/hip_fp16.h>

typedef _Float16 f16x8 __attribute__((ext_vector_type(8)));
typedef _Float16 f16x4 __attribute__((ext_vector_type(4)));
typedef float f32x4 __attribute__((ext_vector_type(4)));

#define NB 8
#define NNS 5

// workspace float offsets
// xpF  : 2M halfs = 1M float slots  [0, 1048576)        B-frag packed xp
// l2AF : 1M halfs = 512K floats     [1048576, 1572864)  A-frag packed log2(A+eps)
// srcT : 32768  [1572864, 1605632)   [b][h][j] f32
// dstT : 32768  [1605632, 1638400)   [b][h][i] f32
// xmean: 2048   [1638400, 1640448)
// cs   : 8      [1640448, 1640456)
// WpF  : 64K halfs = 32768 floats   [1640456, 1673224)  B-frag packed Wp

// ---------------------------------------------------------------------------
// K0 merged. blk<256: WpF pack  WpF[nh][nt][kc][lane][u] = Wp[k][f]
//            256<=blk<512: xmean atomic partials
//            blk>=512: l2AF pack l2AF[it][jc][lane][u] = log2(A[i][j]+1e-9)
// lane=(lm,q): f = nh*64+nt*16+lm, k = kc*32+q*8+u ; i = it*16+lm,
// j = jc*32+q*8+u.  All writes coalesced.
// ---------------------------------------------------------------------------
__global__ __launch_bounds__(256) void k_pre(const float* __restrict__ Wp,
                                             const float* __restrict__ x,
                                             const float* __restrict__ A,
                                             __half* __restrict__ WpF,
                                             float* __restrict__ xmean,
                                             __half* __restrict__ l2AF) {
  const int t = threadIdx.x;
  const int blk = blockIdx.x;
  if (blk < 256) {
    const int idx = (blk << 8) + t;
    const int u = idx & 7, lane = (idx >> 3) & 63;
    const int kc = (idx >> 9) & 7, nt = (idx >> 12) & 3, nh = idx >> 14;
    const int f = (nh << 6) + (nt << 4) + (lane & 15);
    const int k = (kc << 5) + (((lane >> 4)) << 3) + u;
    WpF[idx] = __float2half(Wp[(k << 8) + f]);
  } else if (blk < 512) {
    const int row0 = (blk - 256) << 5;
    const int b = row0 >> 10;
    float ps = 0.f;
    #pragma unroll 8
    for (int r = 0; r < 32; ++r) ps += x[(size_t)(row0 + r) * 256 + t];
    atomicAdd(&xmean[(b << 8) + t], ps);
  } else {
    const int idx = ((blk - 512) << 8) + t;
    const int u = idx & 7, lane = (idx >> 3) & 63;
    const int jc = (idx >> 9) & 31, it = idx >> 14;
    const int row = (it << 4) + (lane & 15);
    const int j = (jc << 5) + ((lane >> 4) << 3) + u;
    l2AF[idx] = __float2half(__log2f(A[((size_t)row << 10) + j] + 1e-9f));
  }
}

// ---------------------------------------------------------------------------
// K1: xp = fp16(x @ Wp + bp) written in B-frag order xpF[b][h][jc][nt][lane][u]
// (+ fused src/dst head-scores). Block = 64 rows x 64 cols (nh), 4 waves.
// x staged f16 in LDS (XOR-swizzled rows); WpF frag loads coalesced.
// ---------------------------------------------------------------------------
__global__ __launch_bounds__(256, 4) void k_projM(
    const float* __restrict__ x, const __half* __restrict__ WpF,
    const float* __restrict__ bp, const float* __restrict__ att_w,
    __half* __restrict__ xpF, float* __restrict__ srcT,
    float* __restrict__ dstT) {
  __shared__ __align__(16) __half xs[64 * 256];   // 32 KB
  const int t = threadIdx.x;
  const int l = t & 63, w = t >> 6;
  const int lm = l & 15, q = l >> 4;
  const int rg = blockIdx.x >> 2, nh = blockIdx.x & 3;
  const int row0 = rg << 6;

  // stage x rows (64 x 256) -> f16 LDS, XOR swizzle byte^=(row&7)<<4
  #pragma unroll
  for (int it = 0; it < 16; ++it) {
    const int fi = (it << 8) + t;
    const int row = fi >> 6, c4 = fi & 63;
    const f32x4 v = *(const f32x4*)(x + (size_t)(row0 + row) * 256 + (c4 << 2));
    f16x4 hv;
    #pragma unroll
    for (int u = 0; u < 4; ++u) hv[u] = (_Float16)v[u];
    const int byte = (row << 9) + (c4 << 3);
    *(f16x4*)((char*)xs + (byte ^ ((row & 7) << 4))) = hv;
  }
  __syncthreads();

  const char* ar = (char*)xs + (((w << 4) + lm) << 9);
  const int xa = (lm & 7) << 4;
  const __half* Bw = WpF + (nh << 14) + (l << 3);

  f32x4 acc0 = {0.f, 0.f, 0.f, 0.f}, acc1 = acc0, acc2 = acc0, acc3 = acc0;
  #pragma unroll
  for (int kc = 0; kc < 8; ++kc) {
    const f16x8 af =
        *(const f16x8*)(ar + ((((kc << 5) + (q << 3)) << 1) ^ xa));
    const f16x8 b0 = *(const f16x8*)(Bw + (kc << 9));
    const f16x8 b1 = *(const f16x8*)(Bw + (kc << 9) + 4096);
    const f16x8 b2 = *(const f16x8*)(Bw + (kc << 9) + 8192);
    const f16x8 b3 = *(const f16x8*)(Bw + (kc << 9) + 12288);
    acc0 = __builtin_amdgcn_mfma_f32_16x16x32_f16(af, b0, acc0, 0, 0, 0);
    acc1 = __builtin_amdgcn_mfma_f32_16x16x32_f16(af, b1, acc1, 0, 0, 0);
    acc2 = __builtin_amdgcn_mfma_f32_16x16x32_f16(af, b2, acc2, 0, 0, 0);
    acc3 = __builtin_amdgcn_mfma_f32_16x16x32_f16(af, b3, acc3, 0, 0, 0);
  }

  // epilogue: C/D layout col(d_local)=lane&15, row(i_local)=(lane>>4)*4+reg
  const int Rw = row0 + (w << 4);
  const int b = Rw >> 10;
  const int il = (Rw & 1023) + (q << 2);
  const int jc = il >> 5, lq = (il >> 3) & 3, u0 = il & 7;
  const int lane_o = (lq << 4) + lm;
  f32x4 accs[4] = {acc0, acc1, acc2, acc3};
  float wsn[4], wdn[4];
  #pragma unroll
  for (int n = 0; n < 4; ++n) {
    const int d = (n << 4) + lm;
    wsn[n] = att_w[d];
    wdn[n] = att_w[64 + d];
  }
  const size_t base = ((((size_t)((b << 2) + nh) << 5) + jc) << 2);
  #pragma unroll
  for (int n = 0; n < 4; ++n) {
    const float bias = bp[(nh << 6) + (n << 4) + lm];
    f16x4 o;
    #pragma unroll
    for (int reg = 0; reg < 4; ++reg) {
      accs[n][reg] += bias;
      o[reg] = (_Float16)accs[n][reg];
    }
    *(f16x4*)(xpF + (((base + n) << 9) + (lane_o << 3) + u0)) = o;
  }
  #pragma unroll
  for (int reg = 0; reg < 4; ++reg) {
    float ss = 0.f, ds = 0.f;
    #pragma unroll
    for (int n = 0; n < 4; ++n) {
      ss = fmaf(accs[n][reg], wsn[n], ss);
      ds = fmaf(accs[n][reg], wdn[n], ds);
    }
    #pragma unroll
    for (int off = 1; off < 16; off <<= 1) {
      ss += __shfl_xor(ss, off);
      ds += __shfl_xor(ds, off);
    }
    if (lm == 0) {
      const int i = il + reg;
      srcT[(((b << 2) + nh) << 10) + i] = ss;
      dstT[(((b << 2) + nh) << 10) + i] = ds;
    }
  }
}

// ---------------------------------------------------------------------------
// K2: tiny per-batch MLP head -> s_logits (output 1), c_s scalar.
// ---------------------------------------------------------------------------
__global__ __launch_bounds__(256) void k_head(
    const float* __restrict__ Ws1, const float* __restrict__ bs1,
    const float* __restrict__ Ws2, const float* __restrict__ bs2,
    const float* __restrict__ Wc1, const float* __restrict__ bc1,
    const float* __restrict__ Wc2, const float* __restrict__ bc2,
    const float* __restrict__ att_w, const float* __restrict__ xmean,
    float* __restrict__ cs_ws, float* __restrict__ out_slogits) {
  __shared__ float xm[256];
  __shared__ float h1p[2][128];
  __shared__ float h1[128];
  __shared__ float sl[NNS];
  __shared__ float sp[NNS];
  __shared__ float cc1[64];
  __shared__ float cvec[64];
  const int b = blockIdx.x, t = threadIdx.x;
  xm[t] = xmean[b * 256 + t] * (1.f / 1024.f);
  __syncthreads();
  {
    const int kh = t >> 7, f = t & 127;
    const float* wcol = Ws1 + (kh << 7) * 128 + f;
    const float* xk = xm + (kh << 7);
    float a = 0.f;
    #pragma unroll 8
    for (int k = 0; k < 128; ++k) a = fmaf(xk[k], wcol[k * 128], a);
    h1p[kh][f] = a;
  }
  __syncthreads();
  if (t < 128) h1[t] = fmaxf(h1p[0][t] + h1p[1][t] + bs1[t], 0.f);
  __syncthreads();
  if (t < NNS) {
    float a = bs2[t];
    #pragma unroll 8
    for (int k = 0; k < 128; ++k) a = fmaf(h1[k], Ws2[k * NNS + t], a);
    sl[t] = a;
    out_slogits[b * NNS + t] = a;
  }
  __syncthreads();
  if (t == 0) {
    float m = sl[0];
    for (int n = 1; n < NNS; ++n) m = fmaxf(m, sl[n]);
    float s = 0.f;
    for (int n = 0; n < NNS; ++n) { sp[n] = expf(sl[n] - m); s += sp[n]; }
    for (int n = 0; n < NNS; ++n) sp[n] /= s;
  }
  __syncthreads();
  if (t < 64) {
    float a = bc1[t];
    #pragma unroll
    for (int n = 0; n < NNS; ++n) a = fmaf(sp[n], Wc1[n * 64 + t], a);
    cc1[t] = fmaxf(a, 0.f);
  }
  __syncthreads();
  if (t < 64) {
    float a = bc2[t];
    #pragma unroll 8
    for (int m = 0; m < 64; ++m) a = fmaf(cc1[m], Wc2[m * 64 + t], a);
    cvec[t] = a;
  }
  __syncthreads();
  if (t < 64) {
    float v = cvec[t] * att_w[128 + t];
    #pragma unroll
    for (int m = 32; m; m >>= 1) v += __shfl_xor(v, m);
    if (t == 0) cs_ws[b] = v;
  }
}

// ---------------------------------------------------------------------------
// K3: attention. Block = (b, 16 i-rows), 1024 thr = 16 waves (4 h x 4 jq).
// Grid 512 -> 2 blocks/CU -> 8 waves/SIMD. All frag loads lane-contiguous
// 1KB bursts. Scores computed once, in-register, in A-frag layout. Single
// barrier: 4-way j-partial reduce + denominators through padded LDS.
// ---------------------------------------------------------------------------
__global__ __launch_bounds__(1024, 8) void k_attn(
    const __half* __restrict__ xpF, const __half* __restrict__ l2AF,
    const float* __restrict__ srcT, const float* __restrict__ dstT,
    const float* __restrict__ cs_ws, const float* __restrict__ lam,
    float* __restrict__ out) {
  __shared__ float red[3][4][4][16][18];   // [jq-1][h][nt][irow][dcol+pad]
  __shared__ float dsum[4][4][16];         // [h][jq][irow]
  const int t = threadIdx.x;
  const int l = t & 63, w = t >> 6;
  const int h = w & 3, jq = w >> 2;
  const int lm = l & 15, q = l >> 4;
  const int b = blockIdx.x >> 6;
  const int tile = blockIdx.x & 63;
  const int i0 = tile << 4;

  const float csv = cs_ws[b];
  const float lamln2 = lam[h] * 0.69314718056f;  // lam*ln(A) = lamln2*log2(A)
  const float dstc = dstT[(((b << 2) + h) << 10) + i0 + lm] + csv;

  const __half* Lp =
      l2AF + ((((size_t)(tile << 5) + (jq << 3)) << 6) + l) * 8;
  const float* Sp = srcT + (((b << 2) + h) << 10) + (jq << 8) + (q << 3);
  const __half* Bp =
      xpF + ((((size_t)((b << 2) + h) << 5) + (jq << 3)) << 11) + (l << 3);

  f32x4 acc0 = {0.f, 0.f, 0.f, 0.f}, acc1 = acc0, acc2 = acc0, acc3 = acc0;
  float sum = 0.f;

  #pragma unroll
  for (int kk = 0; kk < 8; ++kk) {
    const f16x8 la = *(const f16x8*)(Lp + (kk << 9));
    const f16x8 bf0 = *(const f16x8*)(Bp + (kk << 11));
    const f16x8 bf1 = *(const f16x8*)(Bp + (kk << 11) + 512);
    const f16x8 bf2 = *(const f16x8*)(Bp + (kk << 11) + 1024);
    const f16x8 bf3 = *(const f16x8*)(Bp + (kk << 11) + 1536);
    const f32x4 s0 = *(const f32x4*)(Sp + (kk << 5));
    const f32x4 s1 = *(const f32x4*)(Sp + (kk << 5) + 4);
    f16x8 af;
    #pragma unroll
    for (int u = 0; u < 4; ++u) {
      float e0 = s0[u] + dstc;
      e0 = fmaxf(e0, 0.2f * e0);                    // leaky relu 0.2
      const float p0 = __expf(fmaf(lamln2, (float)la[u], e0));
      sum += p0;
      af[u] = (_Float16)p0;
      float e1 = s1[u] + dstc;
      e1 = fmaxf(e1, 0.2f * e1);
      const float p1 = __expf(fmaf(lamln2, (float)la[u + 4], e1));
      sum += p1;
      af[u + 4] = (_Float16)p1;
    }
    acc0 = __builtin_amdgcn_mfma_f32_16x16x32_f16(af, bf0, acc0, 0, 0, 0);
    acc1 = __builtin_amdgcn_mfma_f32_16x16x32_f16(af, bf1, acc1, 0, 0, 0);
    acc2 = __builtin_amdgcn_mfma_f32_16x16x32_f16(af, bf2, acc2, 0, 0, 0);
    acc3 = __builtin_amdgcn_mfma_f32_16x16x32_f16(af, bf3, acc3, 0, 0, 0);
  }

  // per-row partial denominators for this j-quarter (lane lm holds row lm)
  sum += __shfl_xor(sum, 16);
  sum += __shfl_xor(sum, 32);
  if (l < 16) dsum[h][jq][lm] = sum;
  if (jq != 0) {
    #pragma unroll
    for (int reg = 0; reg < 4; ++reg) {
      const int mrow = (q << 2) + reg;
      red[jq - 1][h][0][mrow][lm] = acc0[reg];
      red[jq - 1][h][1][mrow][lm] = acc1[reg];
      red[jq - 1][h][2][mrow][lm] = acc2[reg];
      red[jq - 1][h][3][mrow][lm] = acc3[reg];
    }
  }
  __syncthreads();
  if (jq == 0) {
    // C/D layout: dcol = lane&15, irow = (lane>>4)*4 + reg
    float* ob =
        out + (((size_t)((b << 10) + i0)) << 8) + (h << 6) + lm;
    #pragma unroll
    for (int reg = 0; reg < 4; ++reg) {
      const int mrow = (q << 2) + reg;
      const float dv = 1.f / (dsum[h][0][mrow] + dsum[h][1][mrow] +
                              dsum[h][2][mrow] + dsum[h][3][mrow]);
      const float v0 = acc0[reg] + red[0][h][0][mrow][lm] +
                       red[1][h][0][mrow][lm] + red[2][h][0][mrow][lm];
      const float v1 = acc1[reg] + red[0][h][1][mrow][lm] +
                       red[1][h][1][mrow][lm] + red[2][h][1][mrow][lm];
      const float v2 = acc2[reg] + red[0][h][2][mrow][lm] +
                       red[1][h][2][mrow][lm] + red[2][h][2][mrow][lm];
      const float v3 = acc3[reg] + red[0][h][3][mrow][lm] +
                       red[1][h][3][mrow][lm] + red[2][h][3][mrow][lm];
      float* orow = ob + ((size_t)mrow << 8);
      orow[0] = v0 * dv;
      orow[16] = v1 * dv;
      orow[32] = v2 * dv;
      orow[48] = v3 * dv;
    }
  }
}

extern "C" void kernel_launch(void* const* d_in, const int* in_sizes, int n_in,
                              void* d_out, int out_size, void* d_ws,
                              size_t ws_size, hipStream_t stream) {
  const float* x     = (const float*)d_in[0];
  const float* A     = (const float*)d_in[1];
  const float* Wp    = (const float*)d_in[2];
  const float* bp    = (const float*)d_in[3];
  const float* Ws1   = (const float*)d_in[4];
  const float* bs1   = (const float*)d_in[5];
  const float* Ws2   = (const float*)d_in[6];
  const float* bs2   = (const float*)d_in[7];
  const float* Wc1   = (const float*)d_in[8];
  const float* bc1   = (const float*)d_in[9];
  const float* Wc2   = (const float*)d_in[10];
  const float* bc2   = (const float*)d_in[11];
  const float* att_w = (const float*)d_in[12];
  const float* lam   = (const float*)d_in[13];
  float* out = (float*)d_out;
  float* ws  = (float*)d_ws;

  __half* xpF  = (__half*)ws;                 // 2M halfs
  __half* l2AF = (__half*)(ws + 1048576);     // 1M halfs
  float* srcT  = ws + 1572864;
  float* dstT  = ws + 1605632;
  float* xmean = ws + 1638400;
  float* cs    = ws + 1640448;
  __half* WpF  = (__half*)(ws + 1640456);

  hipMemsetAsync(xmean, 0, 2048 * sizeof(float), stream);

  k_pre<<<dim3(4608), dim3(256), 0, stream>>>(Wp, x, A, WpF, xmean, l2AF);
  k_projM<<<dim3(512), dim3(256), 0, stream>>>(x, WpF, bp, att_w, xpF, srcT,
                                               dstT);
  k_head<<<dim3(NB), dim3(256), 0, stream>>>(Ws1, bs1, Ws2, bs2, Wc1, bc1,
                                             Wc2, bc2, att_w, xmean, cs,
                                             out + NB * 1024 * 256);
  k_attn<<<dim3(512), dim3(1024), 0, stream>>>(xpF, l2AF, srcT, dstT, cs, lam,
                                               out);
}

// Round 8
// 128.985 us; speedup vs baseline: 1.4261x; 1.0076x over previous
//
#include <hip/hip_runtime.h>
#include <hip/hip_fp16.h>

typedef _Float16 f16x8 __attribute__((ext_vector_type(8)));
typedef _Float16 f16x4 __attribute__((ext_vector_type(4)));
typedef float f32x4 __attribute__((ext_vector_type(4)));

#define NB 8
#define NNS 5

// workspace float offsets
// xpF  : 2M halfs   [0, 1048576)          B-frag packed xp
// l2AF : 1M halfs   [1048576, 1572864)    A-frag packed log2(A+eps)
// xF   : 2M halfs   [1572864, 2621440)    A-frag packed fp16(x)
// srcT : 32768      [2621440, 2654208)    [b][h][j] f32
// dstT : 32768      [2654208, 2686976)    [b][h][i] f32
// xmean: 2048       [2686976, 2689024)
// cs   : 8          [2689024, 2689032)
// WpF  : 64K halfs  [2689032, 2721800)    B-frag packed Wp

// ---------------------------------------------------------------------------
// K0 merged. blk<256: WpF pack WpF[nh][nt][kc][lane][u] = Wp[k][f]
//   256<=blk<512: x-pass — stage 32 rows in LDS, xmean atomic partial,
//                 xF A-frag pack  xF[rt][kc][lane][u] = fp16(x[row][k])
//   blk>=512: l2AF pack l2AF[it][jc][lane][u] = fp16(log2(A[i][j]+1e-9))
// frag decode: row/f = .. + (lane&15), k/j = ..*32 + (lane>>4)*8 + u.
// ---------------------------------------------------------------------------
__global__ __launch_bounds__(256) void k_pre(const float* __restrict__ Wp,
                                             const float* __restrict__ x,
                                             const float* __restrict__ A,
                                             __half* __restrict__ WpF,
                                             float* __restrict__ xmean,
                                             __half* __restrict__ xF,
                                             __half* __restrict__ l2AF) {
  __shared__ __align__(16) float xs[32][260];
  const int t = threadIdx.x;
  const int blk = blockIdx.x;
  if (blk < 256) {
    const int idx = (blk << 8) + t;
    const int u = idx & 7, lane = (idx >> 3) & 63;
    const int kc = (idx >> 9) & 7, nt = (idx >> 12) & 3, nh = idx >> 14;
    const int f = (nh << 6) + (nt << 4) + (lane & 15);
    const int k = (kc << 5) + ((lane >> 4) << 3) + u;
    WpF[idx] = __float2half(Wp[(k << 8) + f]);
  } else if (blk < 512) {
    const int row0 = (blk - 256) << 5;
    const int b = row0 >> 10;
    const int rt0 = row0 >> 4;
    float ps = 0.f;
    #pragma unroll 8
    for (int r = 0; r < 32; ++r) {
      const float v = x[(size_t)(row0 + r) * 256 + t];
      xs[r][t] = v;
      ps += v;
    }
    atomicAdd(&xmean[(b << 8) + t], ps);
    __syncthreads();
    #pragma unroll
    for (int it = 0; it < 4; ++it) {
      const int oi = it * 256 + t;           // o = oi*8
      const int lane = oi & 63;
      const int kc = (oi >> 6) & 7;
      const int rtl = oi >> 9;
      const int row_l = (rtl << 4) + (lane & 15);
      const int k0 = (kc << 5) + ((lane >> 4) << 3);
      const f32x4 va = *(const f32x4*)&xs[row_l][k0];
      const f32x4 vb = *(const f32x4*)&xs[row_l][k0 + 4];
      f16x8 hv;
      #pragma unroll
      for (int u = 0; u < 4; ++u) {
        hv[u] = (_Float16)va[u];
        hv[u + 4] = (_Float16)vb[u];
      }
      *(f16x8*)(xF + (((size_t)(rt0 + rtl)) << 12) + (kc << 9) + (lane << 3)) =
          hv;
    }
  } else {
    const int idx = ((blk - 512) << 8) + t;
    const int u = idx & 7, lane = (idx >> 3) & 63;
    const int jc = (idx >> 9) & 31, it = idx >> 14;
    const int row = (it << 4) + (lane & 15);
    const int j = (jc << 5) + ((lane >> 4) << 3) + u;
    l2AF[idx] = __float2half(__log2f(A[((size_t)row << 10) + j] + 1e-9f));
  }
}

// ---------------------------------------------------------------------------
// K1: xp = fp16(x @ Wp + bp) in B-frag order (+ fused src/dst scores).
// No LDS: A-frags from xF, B-frags from WpF — all 1KB bursts.
// Grid 512: rg = blk>>2, nh = blk&3. Wave w: rt = rg*4 + w.
// ---------------------------------------------------------------------------
__global__ __launch_bounds__(256, 4) void k_projM(
    const __half* __restrict__ xF, const __half* __restrict__ WpF,
    const float* __restrict__ bp, const float* __restrict__ att_w,
    __half* __restrict__ xpF, float* __restrict__ srcT,
    float* __restrict__ dstT) {
  const int t = threadIdx.x;
  const int l = t & 63, w = t >> 6;
  const int lm = l & 15, q = l >> 4;
  const int rg = blockIdx.x >> 2, nh = blockIdx.x & 3;
  const int rt = (rg << 2) + w;
  const int R0 = rt << 4;

  const __half* Ap = xF + (((size_t)rt) << 12) + (l << 3);
  const __half* Bw = WpF + (nh << 14) + (l << 3);

  f16x8 ah[8];
  #pragma unroll
  for (int kc = 0; kc < 8; ++kc) ah[kc] = *(const f16x8*)(Ap + (kc << 9));

  f32x4 acc0 = {0.f, 0.f, 0.f, 0.f}, acc1 = acc0, acc2 = acc0, acc3 = acc0;
  #pragma unroll
  for (int kc = 0; kc < 8; ++kc) {
    const f16x8 b0 = *(const f16x8*)(Bw + (kc << 9));
    const f16x8 b1 = *(const f16x8*)(Bw + (kc << 9) + 4096);
    const f16x8 b2 = *(const f16x8*)(Bw + (kc << 9) + 8192);
    const f16x8 b3 = *(const f16x8*)(Bw + (kc << 9) + 12288);
    acc0 = __builtin_amdgcn_mfma_f32_16x16x32_f16(ah[kc], b0, acc0, 0, 0, 0);
    acc1 = __builtin_amdgcn_mfma_f32_16x16x32_f16(ah[kc], b1, acc1, 0, 0, 0);
    acc2 = __builtin_amdgcn_mfma_f32_16x16x32_f16(ah[kc], b2, acc2, 0, 0, 0);
    acc3 = __builtin_amdgcn_mfma_f32_16x16x32_f16(ah[kc], b3, acc3, 0, 0, 0);
  }

  // epilogue: C/D layout col(d_local)=lane&15, row(i_local)=(lane>>4)*4+reg
  const int b = R0 >> 10;
  const int il = (R0 & 1023) + (q << 2);
  const int jc = il >> 5, lq = (il >> 3) & 3, u0 = il & 7;
  const int lane_o = (lq << 4) + lm;
  f32x4 accs[4] = {acc0, acc1, acc2, acc3};
  float wsn[4], wdn[4];
  #pragma unroll
  for (int n = 0; n < 4; ++n) {
    const int d = (n << 4) + lm;
    wsn[n] = att_w[d];
    wdn[n] = att_w[64 + d];
  }
  const size_t base = ((((size_t)((b << 2) + nh) << 5) + jc) << 2);
  #pragma unroll
  for (int n = 0; n < 4; ++n) {
    const float bias = bp[(nh << 6) + (n << 4) + lm];
    f16x4 o;
    #pragma unroll
    for (int reg = 0; reg < 4; ++reg) {
      accs[n][reg] += bias;
      o[reg] = (_Float16)accs[n][reg];
    }
    *(f16x4*)(xpF + (((base + n) << 9) + (lane_o << 3) + u0)) = o;
  }
  #pragma unroll
  for (int reg = 0; reg < 4; ++reg) {
    float ss = 0.f, ds = 0.f;
    #pragma unroll
    for (int n = 0; n < 4; ++n) {
      ss = fmaf(accs[n][reg], wsn[n], ss);
      ds = fmaf(accs[n][reg], wdn[n], ds);
    }
    #pragma unroll
    for (int off = 1; off < 16; off <<= 1) {
      ss += __shfl_xor(ss, off);
      ds += __shfl_xor(ds, off);
    }
    if (lm == 0) {
      const int i = il + reg;
      srcT[(((b << 2) + nh) << 10) + i] = ss;
      dstT[(((b << 2) + nh) << 10) + i] = ds;
    }
  }
}

// ---------------------------------------------------------------------------
// K2: tiny per-batch MLP head -> s_logits (output 1), c_s scalar.
// ---------------------------------------------------------------------------
__global__ __launch_bounds__(256) void k_head(
    const float* __restrict__ Ws1, const float* __restrict__ bs1,
    const float* __restrict__ Ws2, const float* __restrict__ bs2,
    const float* __restrict__ Wc1, const float* __restrict__ bc1,
    const float* __restrict__ Wc2, const float* __restrict__ bc2,
    const float* __restrict__ att_w, const float* __restrict__ xmean,
    float* __restrict__ cs_ws, float* __restrict__ out_slogits) {
  __shared__ float xm[256];
  __shared__ float h1p[2][128];
  __shared__ float h1[128];
  __shared__ float sl[NNS];
  __shared__ float sp[NNS];
  __shared__ float cc1[64];
  __shared__ float cvec[64];
  const int b = blockIdx.x, t = threadIdx.x;
  xm[t] = xmean[b * 256 + t] * (1.f / 1024.f);
  __syncthreads();
  {
    const int kh = t >> 7, f = t & 127;
    const float* wcol = Ws1 + (kh << 7) * 128 + f;
    const float* xk = xm + (kh << 7);
    float a = 0.f;
    #pragma unroll 8
    for (int k = 0; k < 128; ++k) a = fmaf(xk[k], wcol[k * 128], a);
    h1p[kh][f] = a;
  }
  __syncthreads();
  if (t < 128) h1[t] = fmaxf(h1p[0][t] + h1p[1][t] + bs1[t], 0.f);
  __syncthreads();
  if (t < NNS) {
    float a = bs2[t];
    #pragma unroll 8
    for (int k = 0; k < 128; ++k) a = fmaf(h1[k], Ws2[k * NNS + t], a);
    sl[t] = a;
    out_slogits[b * NNS + t] = a;
  }
  __syncthreads();
  if (t == 0) {
    float m = sl[0];
    for (int n = 1; n < NNS; ++n) m = fmaxf(m, sl[n]);
    float s = 0.f;
    for (int n = 0; n < NNS; ++n) { sp[n] = expf(sl[n] - m); s += sp[n]; }
    for (int n = 0; n < NNS; ++n) sp[n] /= s;
  }
  __syncthreads();
  if (t < 64) {
    float a = bc1[t];
    #pragma unroll
    for (int n = 0; n < NNS; ++n) a = fmaf(sp[n], Wc1[n * 64 + t], a);
    cc1[t] = fmaxf(a, 0.f);
  }
  __syncthreads();
  if (t < 64) {
    float a = bc2[t];
    #pragma unroll 8
    for (int m = 0; m < 64; ++m) a = fmaf(cc1[m], Wc2[m * 64 + t], a);
    cvec[t] = a;
  }
  __syncthreads();
  if (t < 64) {
    float v = cvec[t] * att_w[128 + t];
    #pragma unroll
    for (int m = 32; m; m >>= 1) v += __shfl_xor(v, m);
    if (t == 0) cs_ws[b] = v;
  }
}

// ---------------------------------------------------------------------------
// K3: attention. Block = (b, 16 i-rows), 512 thr = 8 waves (4 h x 2 jh).
// launch_bounds(512,4) -> 128 VGPR: room for 1-step rotating prefetch of all
// burst loads. Scores once, in-register, A-frag layout. One barrier, 2-way
// j-half reduce through padded LDS.
// ---------------------------------------------------------------------------
__global__ __launch_bounds__(512, 4) void k_attn(
    const __half* __restrict__ xpF, const __half* __restrict__ l2AF,
    const float* __restrict__ srcT, const float* __restrict__ dstT,
    const float* __restrict__ cs_ws, const float* __restrict__ lam,
    float* __restrict__ out) {
  __shared__ float red[4][4][16][18];   // [h][nt][irow][dcol+pad]
  __shared__ float dsum[4][2][16];      // [h][jh][irow]
  const int t = threadIdx.x;
  const int l = t & 63, w = t >> 6;
  const int h = w & 3, jh = w >> 2;
  const int lm = l & 15, q = l >> 4;
  const int b = blockIdx.x >> 6;
  const int tile = blockIdx.x & 63;
  const int i0 = tile << 4;

  const float csv = cs_ws[b];
  const float lamln2 = lam[h] * 0.69314718056f;  // lam*ln(A) = lamln2*log2(A)
  const float dstc = dstT[(((b << 2) + h) << 10) + i0 + lm] + csv;

  const __half* Lp = l2AF + (tile << 14) + (jh << 13) + (l << 3);
  const float* Sp = srcT + (((b << 2) + h) << 10) + (jh << 9) + (q << 3);
  const __half* Bp =
      xpF + (((size_t)((b << 2) + h)) << 16) + (jh << 15) + (l << 3);

  f32x4 acc0 = {0.f, 0.f, 0.f, 0.f}, acc1 = acc0, acc2 = acc0, acc3 = acc0;
  float sum = 0.f;

  f16x8 la = *(const f16x8*)Lp;
  f32x4 s0 = *(const f32x4*)Sp;
  f32x4 s1 = *(const f32x4*)(Sp + 4);
  f16x8 bf0 = *(const f16x8*)Bp;
  f16x8 bf1 = *(const f16x8*)(Bp + 512);
  f16x8 bf2 = *(const f16x8*)(Bp + 1024);
  f16x8 bf3 = *(const f16x8*)(Bp + 1536);

  #pragma unroll 4
  for (int kk = 0; kk < 16; ++kk) {
    const int nk = (kk < 15) ? kk + 1 : kk;
    const f16x8 la_n = *(const f16x8*)(Lp + (nk << 9));
    const f32x4 s0_n = *(const f32x4*)(Sp + (nk << 5));
    const f32x4 s1_n = *(const f32x4*)(Sp + (nk << 5) + 4);
    const f16x8 b0_n = *(const f16x8*)(Bp + (nk << 11));
    const f16x8 b1_n = *(const f16x8*)(Bp + (nk << 11) + 512);
    const f16x8 b2_n = *(const f16x8*)(Bp + (nk << 11) + 1024);
    const f16x8 b3_n = *(const f16x8*)(Bp + (nk << 11) + 1536);

    f16x8 af;
    #pragma unroll
    for (int u = 0; u < 4; ++u) {
      float e0 = s0[u] + dstc;
      e0 = fmaxf(e0, 0.2f * e0);                    // leaky relu 0.2
      const float p0 = __expf(fmaf(lamln2, (float)la[u], e0));
      sum += p0;
      af[u] = (_Float16)p0;
      float e1 = s1[u] + dstc;
      e1 = fmaxf(e1, 0.2f * e1);
      const float p1 = __expf(fmaf(lamln2, (float)la[u + 4], e1));
      sum += p1;
      af[u + 4] = (_Float16)p1;
    }
    acc0 = __builtin_amdgcn_mfma_f32_16x16x32_f16(af, bf0, acc0, 0, 0, 0);
    acc1 = __builtin_amdgcn_mfma_f32_16x16x32_f16(af, bf1, acc1, 0, 0, 0);
    acc2 = __builtin_amdgcn_mfma_f32_16x16x32_f16(af, bf2, acc2, 0, 0, 0);
    acc3 = __builtin_amdgcn_mfma_f32_16x16x32_f16(af, bf3, acc3, 0, 0, 0);
    la = la_n; s0 = s0_n; s1 = s1_n;
    bf0 = b0_n; bf1 = b1_n; bf2 = b2_n; bf3 = b3_n;
  }

  // per-row partial denominators (lane lm holds row lm of this jh half)
  sum += __shfl_xor(sum, 16);
  sum += __shfl_xor(sum, 32);
  if (l < 16) dsum[h][jh][lm] = sum;
  if (jh == 1) {
    #pragma unroll
    for (int reg = 0; reg < 4; ++reg) {
      const int mrow = (q << 2) + reg;
      red[h][0][mrow][lm] = acc0[reg];
      red[h][1][mrow][lm] = acc1[reg];
      red[h][2][mrow][lm] = acc2[reg];
      red[h][3][mrow][lm] = acc3[reg];
    }
  }
  __syncthreads();
  if (jh == 0) {
    // C/D layout: dcol = lane&15, irow = (lane>>4)*4 + reg
    float* ob = out + (((size_t)((b << 10) + i0)) << 8) + (h << 6) + lm;
    #pragma unroll
    for (int reg = 0; reg < 4; ++reg) {
      const int mrow = (q << 2) + reg;
      const float dv = 1.f / (dsum[h][0][mrow] + dsum[h][1][mrow]);
      float* orow = ob + ((size_t)mrow << 8);
      orow[0] = (acc0[reg] + red[h][0][mrow][lm]) * dv;
      orow[16] = (acc1[reg] + red[h][1][mrow][lm]) * dv;
      orow[32] = (acc2[reg] + red[h][2][mrow][lm]) * dv;
      orow[48] = (acc3[reg] + red[h][3][mrow][lm]) * dv;
    }
  }
}

extern "C" void kernel_launch(void* const* d_in, const int* in_sizes, int n_in,
                              void* d_out, int out_size, void* d_ws,
                              size_t ws_size, hipStream_t stream) {
  const float* x     = (const float*)d_in[0];
  const float* A     = (const float*)d_in[1];
  const float* Wp    = (const float*)d_in[2];
  const float* bp    = (const float*)d_in[3];
  const float* Ws1   = (const float*)d_in[4];
  const float* bs1   = (const float*)d_in[5];
  const float* Ws2   = (const float*)d_in[6];
  const float* bs2   = (const float*)d_in[7];
  const float* Wc1   = (const float*)d_in[8];
  const float* bc1   = (const float*)d_in[9];
  const float* Wc2   = (const float*)d_in[10];
  const float* bc2   = (const float*)d_in[11];
  const float* att_w = (const float*)d_in[12];
  const float* lam   = (const float*)d_in[13];
  float* out = (float*)d_out;
  float* ws  = (float*)d_ws;

  __half* xpF  = (__half*)ws;                 // 2M halfs
  __half* l2AF = (__half*)(ws + 1048576);     // 1M halfs
  __half* xF   = (__half*)(ws + 1572864);     // 2M halfs
  float* srcT  = ws + 2621440;
  float* dstT  = ws + 2654208;
  float* xmean = ws + 2686976;
  float* cs    = ws + 2689024;
  __half* WpF  = (__half*)(ws + 2689032);

  hipMemsetAsync(xmean, 0, 2048 * sizeof(float), stream);

  k_pre<<<dim3(4608), dim3(256), 0, stream>>>(Wp, x, A, WpF, xmean, xF, l2AF);
  k_projM<<<dim3(512), dim3(256), 0, stream>>>(xF, WpF, bp, att_w, xpF, srcT,
                                               dstT);
  k_head<<<dim3(NB), dim3(256), 0, stream>>>(Ws1, bs1, Ws2, bs2, Wc1, bc1,
                                             Wc2, bc2, att_w, xmean, cs,
                                             out + NB * 1024 * 256);
  k_attn<<<dim3(512), dim3(512), 0, stream>>>(xpF, l2AF, srcT, dstT, cs, lam,
                                              out);
}